// Round 13
// baseline (160.952 us; speedup 1.0000x reference)
//
#include <hip/hip_runtime.h>

#define NB   4
#define C_IN 256
#define CQD  64
#define NPT  4096
#define L2E  1.44269504088896f

typedef __attribute__((ext_vector_type(8))) short bf16x8;
typedef __attribute__((ext_vector_type(4))) float f32x4;
typedef unsigned short u16;
typedef unsigned int   u32;

#define EXP2F(x)      __builtin_amdgcn_exp2f(x)
#define MFMA32(A,B,C) __builtin_amdgcn_mfma_f32_16x16x32_bf16(A,B,C,0,0,0)

__device__ __forceinline__ u16 f2bf(float f) {          // RNE (cold paths)
    u32 u = __float_as_uint(f);
    u += 0x7fff + ((u >> 16) & 1);
    return (u16)(u >> 16);
}
// one v_perm: (bf16_trunc(hi)<<16) | bf16_trunc(lo)
__device__ __forceinline__ u32 pack_trunc(float lo, float hi) {
    return __builtin_amdgcn_perm(__float_as_uint(hi), __float_as_uint(lo), 0x07060302u);
}

// ---------------------------------------------------------------------------
// Fragment-major layouts (1 request per wave fragment load):
//   qF/kF: [b][g][half][lane][8] u16, g = seq/16, half = o-chunk/4,
//          lane = 16*q + c16 holds (row 16g+c16, o elems 8*(q+4*half)..+7).
//   vF:    [b][cg][pg][lane][8] u16, cg = c/16, pg = pos/32,
//          lane = 16*q + c16 holds (row 16cg+c16, pos elems 32pg+8q..+7).
//   wbf:   [go*8+kk][lane][8] u16, stride 512/frag (R11, verified).
// ---------------------------------------------------------------------------

// ---------------------------------------------------------------------------
// prep: pack wq|wk|wv into fragment-major bf16 wbf, biases into bias[384]
// ---------------------------------------------------------------------------
__global__ void prep_kernel(
    const float* __restrict__ wq, const float* __restrict__ bq,
    const float* __restrict__ wk, const float* __restrict__ bk,
    const float* __restrict__ wv, const float* __restrict__ bv,
    u16* __restrict__ wbf, float* __restrict__ bias)
{
    const int gid = blockIdx.x*256 + threadIdx.x;
    if (gid < 384*256) {
        const int r = gid >> 8, c = gid & 255;
        const float v = (r < 64) ? wq[r*256 + c]
                      : (r < 128) ? wk[(r-64)*256 + c]
                                  : wv[(r-128)*256 + c];
        // fragment-major destination (stride 512 per fragment)
        const int go  = r >> 4, c16 = r & 15;
        const int kk  = c >> 5, qh  = (c >> 3) & 3, j = c & 7;
        wbf[((size_t)(go*8 + kk))*512 + (16*qh + c16)*8 + j] = f2bf(v);
    } else if (gid < 384*256 + 384) {
        const int r = gid - 384*256;
        bias[r] = (r < 64) ? bq[r] : (r < 128) ? bk[r-64] : bv[r-128];
    }
}

// ---------------------------------------------------------------------------
// proj: MFMA pointwise projections, x read ONCE. Wave w owns tiles T=4*ot+w.
// grid (N/32, B), block 256. Epilogue stores in fragment-major layouts.
// (byte-identical to R11 for attribution)
// ---------------------------------------------------------------------------
union ProjShared {
    u16 x_t[32][264];                            // [n][c] bf16, stride 528B
    struct { u16 qk[32][136]; u16 vl[256][40]; } ep;
};

__global__ __launch_bounds__(256) void proj_kernel(
    const float* __restrict__ x, const u16* __restrict__ wbf,
    const float* __restrict__ bias,
    u16* __restrict__ qF, u16* __restrict__ kF, u16* __restrict__ vF)
{
    __shared__ ProjShared sh;

    const int t  = threadIdx.x;
    const int n0 = blockIdx.x * 32;
    const int b  = blockIdx.y;

    {   // stage x tile transposed -> bf16 LDS
        const int ln = t & 31;
        const int cg = t >> 5;
        #pragma unroll
        for (int rr = 0; rr < 8; rr++) {
            const int c = 4*cg + 32*rr;
            const float f0 = x[((size_t)(b*C_IN + c+0))*NPT + n0 + ln];
            const float f1 = x[((size_t)(b*C_IN + c+1))*NPT + n0 + ln];
            const float f2 = x[((size_t)(b*C_IN + c+2))*NPT + n0 + ln];
            const float f3 = x[((size_t)(b*C_IN + c+3))*NPT + n0 + ln];
            ushort4 u4;
            u4.x = f2bf(f0); u4.y = f2bf(f1); u4.z = f2bf(f2); u4.w = f2bf(f3);
            *(ushort4*)&sh.x_t[ln][c] = u4;
        }
    }
    __syncthreads();

    const int w = t >> 6, l = t & 63, q = l >> 4, c16 = l & 15;

    f32x4 acc[6][2];
    #pragma unroll
    for (int ot = 0; ot < 6; ot++)
        #pragma unroll
        for (int nt = 0; nt < 2; nt++)
            acc[ot][nt] = (f32x4){0.f, 0.f, 0.f, 0.f};

    #pragma unroll
    for (int kk = 0; kk < 8; kk++) {
        const bf16x8 bf0 = *(const bf16x8*)&sh.x_t[c16     ][kk*32 + 8*q];
        const bf16x8 bf1 = *(const bf16x8*)&sh.x_t[16 + c16][kk*32 + 8*q];
        #pragma unroll
        for (int ot = 0; ot < 6; ot++) {
            // fragment-major weight load: lane-contiguous (stride 512)
            const bf16x8 af = *(const bf16x8*)&wbf[((size_t)((4*ot + w)*8 + kk))*512 + l*8];
            acc[ot][0] = MFMA32(af, bf0, acc[ot][0]);
            acc[ot][1] = MFMA32(af, bf1, acc[ot][1]);
        }
    }
    __syncthreads();   // x_t dead; reuse LDS for epilogue staging

    #pragma unroll
    for (int ot = 0; ot < 6; ot++) {
        const int T  = 4*ot + w;
        const int ob = 16*T + 4*q;
        float b0 = bias[ob+0], b1 = bias[ob+1], b2 = bias[ob+2], b3 = bias[ob+3];
        #pragma unroll
        for (int nt = 0; nt < 2; nt++) {
            const f32x4 a = acc[ot][nt];
            const float v0 = a[0]+b0, v1 = a[1]+b1, v2 = a[2]+b2, v3 = a[3]+b3;
            if (ot < 2) {
                uint2 u;
                u.x = (u32)f2bf(v0) | ((u32)f2bf(v1) << 16);
                u.y = (u32)f2bf(v2) | ((u32)f2bf(v3) << 16);
                *(uint2*)&sh.ep.qk[16*nt + c16][16*T + 4*q] = u;
            } else {
                const int cb = 16*T - 128 + 4*q;
                sh.ep.vl[cb+0][16*nt + c16] = f2bf(v0);
                sh.ep.vl[cb+1][16*nt + c16] = f2bf(v1);
                sh.ep.vl[cb+2][16*nt + c16] = f2bf(v2);
                sh.ep.vl[cb+3][16*nt + c16] = f2bf(v3);
            }
        }
    }
    __syncthreads();

    {   // fragment-major global stores
        const int n    = t >> 3;
        const int c    = t & 7;
        const int g    = (n0 + n) >> 4;
        const int lane = 16*(c & 3) + (n & 15);
        const size_t dq = ((size_t)(b*256 + g))*1024 + (size_t)(c >> 2)*512 + lane*8;
        *(uint4*)&qF[dq] = *(uint4*)&sh.ep.qk[n][8*c];
        *(uint4*)&kF[dq] = *(uint4*)&sh.ep.qk[n][64 + 8*c];
        const int cg   = t >> 4, c16v = t & 15;
        const int pg   = n0 >> 5;
        u16* vdst = &vF[(((size_t)(b*16 + cg))*128 + pg)*512 + c16v*8];
        #pragma unroll
        for (int j = 0; j < 4; j++)          // lane 16j+c16v -> offset j*128
            *(uint4*)&vdst[j*128] = *(uint4*)&sh.ep.vl[t][8*j];
    }
}

// ---------------------------------------------------------------------------
// attn (FUSED softmax, R12 VALU-diet): block owns n-tile 64, iterates all m.
// p~ = exp2(s*L2E) unnormalized; normalize at end: out = g*(acc/z) + x.
// R12 changes vs R11 (kill ~100 v_mov/iter, halve LDS read instrs):
//  1. p LDS layout p2[nj][m-octet o][c16][2] uint2: the 8 consecutive
//     m-values a PV reader needs are ONE ds_read_b128 landing directly as
//     the MFMA B-operand (no make_uint4). Writer (w,q) = m-quad g=4w+q
//     stores uint2 at [nj][g>>1][c16][g&1]. Reader (q,c16) reads uint4 at
//     idx nj*256 + kc*64 + q*16 + c16 (64 lanes = contiguous 1KB, 0-conflict).
//  2. v fragments loaded IN-region for the current PV tile (issued after
//     QK, ~300cyc exp2/pack cover for ~200cyc L2 latency) — no carried
//     vac/van arrays, no rotation movs.
// Merged region: [BARRIER; QK_{mt+1}; v-issue_mt; k-prefetch_{mt+2};
// exp+z+write p[buf^1]; PV_mt]. grid 256 = 4b x 64 n-tiles, block 512.
// ---------------------------------------------------------------------------
__global__ __launch_bounds__(512, 2) void attn_kernel(
    const u16* __restrict__ qF, const u16* __restrict__ kF, const u16* __restrict__ vF,
    const float* __restrict__ gamma,
    const float* __restrict__ x, float* __restrict__ out)
{
    __shared__ uint2 p2[2][2048];    // 2 x 16384 B
    __shared__ float zl[8][68];      // per-wave z partials (padded)

    const int t = threadIdx.x;
    const int w = t >> 6, l = t & 63, q = l >> 4, c16 = l & 15;

    const int id  = blockIdx.x;
    const int xcd = id & 7;                    // dispatch round-robins XCDs
    const int jb  = id >> 3;                   // 0..31
    const int b   = xcd >> 1;                  // 2 XCDs per batch -> L2 locality
    const int ntt = ((xcd & 1) << 5) | jb;     // 32 n-tiles per XCD
    const int n0  = ntt * 64;

    // persistent q B-fragments: group gn = ntt*4 + nj (block's 64 n-rows)
    bf16x8 qf[4][2];
    #pragma unroll
    for (int nj = 0; nj < 4; nj++) {
        const u16* qp = &qF[((size_t)(b*256 + ntt*4 + nj))*1024 + l*8];
        qf[nj][0] = *(const bf16x8*)qp;
        qf[nj][1] = *(const bf16x8*)(qp + 512);
    }

    f32x4 acc[2][4];   // [cg][nj]: c = 32w + 16cg + 4q + r, n = n0 + 16nj + c16
    #pragma unroll
    for (int cg = 0; cg < 2; cg++)
        #pragma unroll
        for (int nj = 0; nj < 4; nj++)
            acc[cg][nj] = (f32x4){0.f, 0.f, 0.f, 0.f};

    float zacc[4] = {0.f, 0.f, 0.f, 0.f};   // [nj]: n = n0 + 16nj + c16 partials

    // fragment-major bases (all lane-contiguous)
    const u16* kbase  = &kF[((size_t)(b*256 + w))*1024 + l*8];        // + mt*8192
    const u16* vbase0 = &vF[(((size_t)(b*16 + 2*w))*128)*512 + l*8];  // + (mt*4+kc)*512
    const u16* vbase1 = vbase0 + (size_t)128*512;                     // cg+1

    // p2 indices
    const int g   = 4*w + q;                       // m-quad within 128-m tile
    const int wb0 = (g>>1)*32 + c16*2 + (g&1);     // + nj*512   (uint2 idx)
    const int rb0 = q*16 + c16;                    // + nj*256 + kc*64 (uint4 idx)

    // ---- prologue: m-tile 0 scores -> p2[0]; stage tile-1 k ----
    bf16x8 ka0 = *(const bf16x8*)kbase;
    bf16x8 ka1 = *(const bf16x8*)(kbase + 512);
    {
        f32x4 s[4];
        #pragma unroll
        for (int nj = 0; nj < 4; nj++) {
            f32x4 a = {0.f, 0.f, 0.f, 0.f};
            a = MFMA32(ka0, qf[nj][0], a);
            a = MFMA32(ka1, qf[nj][1], a);
            s[nj] = a;
        }
        #pragma unroll
        for (int nj = 0; nj < 4; nj++) {
            const float p0 = EXP2F(s[nj][0]*L2E);
            const float p1 = EXP2F(s[nj][1]*L2E);
            const float p2v = EXP2F(s[nj][2]*L2E);
            const float p3 = EXP2F(s[nj][3]*L2E);
            zacc[nj] += (p0 + p1) + (p2v + p3);
            uint2 u;
            u.x = pack_trunc(p0, p1);
            u.y = pack_trunc(p2v, p3);
            p2[0][wb0 + nj*512] = u;
        }
    }
    ka0 = *(const bf16x8*)(kbase + 8192);        // m-tile 1
    ka1 = *(const bf16x8*)(kbase + 8192 + 512);

    int buf = 0;
    for (int mt = 0; mt < 31; mt++) {
        __syncthreads();
        // --- merged region ---
        // QK for m-tile mt+1 (k in registers)
        f32x4 s[4];
        #pragma unroll
        for (int nj = 0; nj < 4; nj++) {
            f32x4 a = {0.f, 0.f, 0.f, 0.f};
            a = MFMA32(ka0, qf[nj][0], a);
            a = MFMA32(ka1, qf[nj][1], a);
            s[nj] = a;
        }
        // v fragments for CURRENT PV tile mt (L2 latency covered by exp below)
        bf16x8 va0[4], va1[4];
        #pragma unroll
        for (int kc = 0; kc < 4; kc++) {
            va0[kc] = *(const bf16x8*)(vbase0 + (size_t)(mt*4 + kc)*512);
            va1[kc] = *(const bf16x8*)(vbase1 + (size_t)(mt*4 + kc)*512);
        }
        // k prefetch for m-tile mt+2 (clamped)
        const int m2 = (mt < 30) ? mt + 2 : 31;
        ka0 = *(const bf16x8*)(kbase + (size_t)m2*8192);
        ka1 = *(const bf16x8*)(kbase + (size_t)m2*8192 + 512);

        // exp + z + write p2[buf^1] for m-tile mt+1
        #pragma unroll
        for (int nj = 0; nj < 4; nj++) {
            const float p0 = EXP2F(s[nj][0]*L2E);
            const float p1 = EXP2F(s[nj][1]*L2E);
            const float p2v = EXP2F(s[nj][2]*L2E);
            const float p3 = EXP2F(s[nj][3]*L2E);
            zacc[nj] += (p0 + p1) + (p2v + p3);
            uint2 u;
            u.x = pack_trunc(p0, p1);
            u.y = pack_trunc(p2v, p3);
            p2[buf^1][wb0 + nj*512] = u;
        }

        // PV for m-tile mt: b128 reads land directly as MFMA B-operand
        const uint4* pr = (const uint4*)p2[buf];
        #pragma unroll
        for (int nj = 0; nj < 4; nj++) {
            #pragma unroll
            for (int kc = 0; kc < 4; kc++) {
                const uint4 f = pr[rb0 + nj*256 + kc*64];
                const bf16x8 pf = *(const bf16x8*)&f;
                acc[0][nj] = MFMA32(va0[kc], pf, acc[0][nj]);
                acc[1][nj] = MFMA32(va1[kc], pf, acc[1][nj]);
            }
        }
        buf ^= 1;
    }
    // peeled final m-tile (31): PV only
    __syncthreads();
    {
        bf16x8 va0[4], va1[4];
        #pragma unroll
        for (int kc = 0; kc < 4; kc++) {
            va0[kc] = *(const bf16x8*)(vbase0 + (size_t)(31*4 + kc)*512);
            va1[kc] = *(const bf16x8*)(vbase1 + (size_t)(31*4 + kc)*512);
        }
        const uint4* pr = (const uint4*)p2[buf];
        #pragma unroll
        for (int nj = 0; nj < 4; nj++) {
            #pragma unroll
            for (int kc = 0; kc < 4; kc++) {
                const uint4 f = pr[rb0 + nj*256 + kc*64];
                const bf16x8 pf = *(const bf16x8*)&f;
                acc[0][nj] = MFMA32(va0[kc], pf, acc[0][nj]);
                acc[1][nj] = MFMA32(va1[kc], pf, acc[1][nj]);
            }
        }
    }

    // z: reduce over q (lanes ^16, ^32), then over waves via LDS
    #pragma unroll
    for (int nj = 0; nj < 4; nj++) {
        zacc[nj] += __shfl_xor(zacc[nj], 16, 64);
        zacc[nj] += __shfl_xor(zacc[nj], 32, 64);
    }
    if (q == 0) {
        #pragma unroll
        for (int nj = 0; nj < 4; nj++) zl[w][16*nj + c16] = zacc[nj];
    }
    __syncthreads();

    float rz[4];
    #pragma unroll
    for (int nj = 0; nj < 4; nj++) {
        float zt = 0.f;
        #pragma unroll
        for (int w8 = 0; w8 < 8; w8++) zt += zl[w8][16*nj + c16];
        rz[nj] = 1.0f / zt;
    }

    const float gm = gamma[0];
    #pragma unroll
    for (int cg = 0; cg < 2; cg++)
        #pragma unroll
        for (int nj = 0; nj < 4; nj++)
            #pragma unroll
            for (int r = 0; r < 4; r++) {
                const size_t o = ((size_t)(b*C_IN + 32*w + 16*cg + 4*q + r))*NPT
                               + n0 + 16*nj + c16;
                out[o] = gm*(acc[cg][nj][r]*rz[nj]) + x[o];
            }
}

// ---------------------------------------------------------------------------
extern "C" void kernel_launch(void* const* d_in, const int* in_sizes, int n_in,
                              void* d_out, int out_size, void* d_ws, size_t ws_size,
                              hipStream_t stream)
{
    const float* x     = (const float*)d_in[0];
    const float* wq    = (const float*)d_in[1];
    const float* bq    = (const float*)d_in[2];
    const float* wk    = (const float*)d_in[3];
    const float* bk    = (const float*)d_in[4];
    const float* wv    = (const float*)d_in[5];
    const float* bv    = (const float*)d_in[6];
    const float* gamma = (const float*)d_in[7];
    float* out = (float*)d_out;

    u16* qF  = (u16*)d_ws;                              // 2 MB
    u16* kF  = qF  + (size_t)NB*NPT*CQD;                // 2 MB
    u16* vF  = kF  + (size_t)NB*NPT*CQD;                // 8 MB
    u16* wbf = vF  + (size_t)NB*C_IN*NPT;               // 192 KB
    float* bias = (float*)(wbf + 384*256);              // 384

    prep_kernel<<<dim3(386), 256, 0, stream>>>(wq, bq, wk, bk, wv, bv, wbf, bias);
    proj_kernel<<<dim3(NPT/32, NB), 256, 0, stream>>>(x, wbf, bias, qF, kF, vF);
    attn_kernel<<<dim3(256), 512, 0, stream>>>(qF, kF, vF, gamma, x, out);
}

// Round 14
// 145.215 us; speedup vs baseline: 1.1084x; 1.1084x over previous
//
#include <hip/hip_runtime.h>

#define NB   4
#define C_IN 256
#define CQD  64
#define NPT  4096
#define L2E  1.44269504088896f

typedef __attribute__((ext_vector_type(8))) short bf16x8;
typedef __attribute__((ext_vector_type(4))) float f32x4;
typedef unsigned short u16;
typedef unsigned int   u32;

#define EXP2F(x)      __builtin_amdgcn_exp2f(x)
#define MFMA32(A,B,C) __builtin_amdgcn_mfma_f32_16x16x32_bf16(A,B,C,0,0,0)

__device__ __forceinline__ u16 f2bf(float f) {          // RNE (cold paths)
    u32 u = __float_as_uint(f);
    u += 0x7fff + ((u >> 16) & 1);
    return (u16)(u >> 16);
}
// one v_perm: (bf16_trunc(hi)<<16) | bf16_trunc(lo)
__device__ __forceinline__ u32 pack_trunc(float lo, float hi) {
    return __builtin_amdgcn_perm(__float_as_uint(hi), __float_as_uint(lo), 0x07060302u);
}

// ---------------------------------------------------------------------------
// Fragment-major layouts (1 request per wave fragment load):
//   qF/kF: [b][g][half][lane][8] u16, g = seq/16, half = o-chunk/4,
//          lane = 16*q + c16 holds (row 16g+c16, o elems 8*(q+4*half)..+7).
//   vF:    [b][cg][pg][lane][8] u16, cg = c/16, pg = pos/32,
//          lane = 16*q + c16 holds (row 16cg+c16, pos elems 32pg+8q..+7).
//   wbf:   [go*8+kk][lane][8] u16, stride 512/frag (R11, verified).
// ---------------------------------------------------------------------------

// ---------------------------------------------------------------------------
// prep: pack wq|wk|wv into fragment-major bf16 wbf, biases into bias[384]
// ---------------------------------------------------------------------------
__global__ void prep_kernel(
    const float* __restrict__ wq, const float* __restrict__ bq,
    const float* __restrict__ wk, const float* __restrict__ bk,
    const float* __restrict__ wv, const float* __restrict__ bv,
    u16* __restrict__ wbf, float* __restrict__ bias)
{
    const int gid = blockIdx.x*256 + threadIdx.x;
    if (gid < 384*256) {
        const int r = gid >> 8, c = gid & 255;
        const float v = (r < 64) ? wq[r*256 + c]
                      : (r < 128) ? wk[(r-64)*256 + c]
                                  : wv[(r-128)*256 + c];
        // fragment-major destination (stride 512 per fragment)
        const int go  = r >> 4, c16 = r & 15;
        const int kk  = c >> 5, qh  = (c >> 3) & 3, j = c & 7;
        wbf[((size_t)(go*8 + kk))*512 + (16*qh + c16)*8 + j] = f2bf(v);
    } else if (gid < 384*256 + 384) {
        const int r = gid - 384*256;
        bias[r] = (r < 64) ? bq[r] : (r < 128) ? bk[r-64] : bv[r-128];
    }
}

// ---------------------------------------------------------------------------
// proj: MFMA pointwise projections, x read ONCE. Wave w owns tiles T=4*ot+w.
// grid (N/32, B), block 256. Epilogue stores in fragment-major layouts.
// (byte-identical to R11/R13 for attribution)
// ---------------------------------------------------------------------------
union ProjShared {
    u16 x_t[32][264];                            // [n][c] bf16, stride 528B
    struct { u16 qk[32][136]; u16 vl[256][40]; } ep;
};

__global__ __launch_bounds__(256) void proj_kernel(
    const float* __restrict__ x, const u16* __restrict__ wbf,
    const float* __restrict__ bias,
    u16* __restrict__ qF, u16* __restrict__ kF, u16* __restrict__ vF)
{
    __shared__ ProjShared sh;

    const int t  = threadIdx.x;
    const int n0 = blockIdx.x * 32;
    const int b  = blockIdx.y;

    {   // stage x tile transposed -> bf16 LDS
        const int ln = t & 31;
        const int cg = t >> 5;
        #pragma unroll
        for (int rr = 0; rr < 8; rr++) {
            const int c = 4*cg + 32*rr;
            const float f0 = x[((size_t)(b*C_IN + c+0))*NPT + n0 + ln];
            const float f1 = x[((size_t)(b*C_IN + c+1))*NPT + n0 + ln];
            const float f2 = x[((size_t)(b*C_IN + c+2))*NPT + n0 + ln];
            const float f3 = x[((size_t)(b*C_IN + c+3))*NPT + n0 + ln];
            ushort4 u4;
            u4.x = f2bf(f0); u4.y = f2bf(f1); u4.z = f2bf(f2); u4.w = f2bf(f3);
            *(ushort4*)&sh.x_t[ln][c] = u4;
        }
    }
    __syncthreads();

    const int w = t >> 6, l = t & 63, q = l >> 4, c16 = l & 15;

    f32x4 acc[6][2];
    #pragma unroll
    for (int ot = 0; ot < 6; ot++)
        #pragma unroll
        for (int nt = 0; nt < 2; nt++)
            acc[ot][nt] = (f32x4){0.f, 0.f, 0.f, 0.f};

    #pragma unroll
    for (int kk = 0; kk < 8; kk++) {
        const bf16x8 bf0 = *(const bf16x8*)&sh.x_t[c16     ][kk*32 + 8*q];
        const bf16x8 bf1 = *(const bf16x8*)&sh.x_t[16 + c16][kk*32 + 8*q];
        #pragma unroll
        for (int ot = 0; ot < 6; ot++) {
            // fragment-major weight load: lane-contiguous (stride 512)
            const bf16x8 af = *(const bf16x8*)&wbf[((size_t)((4*ot + w)*8 + kk))*512 + l*8];
            acc[ot][0] = MFMA32(af, bf0, acc[ot][0]);
            acc[ot][1] = MFMA32(af, bf1, acc[ot][1]);
        }
    }
    __syncthreads();   // x_t dead; reuse LDS for epilogue staging

    #pragma unroll
    for (int ot = 0; ot < 6; ot++) {
        const int T  = 4*ot + w;
        const int ob = 16*T + 4*q;
        float b0 = bias[ob+0], b1 = bias[ob+1], b2 = bias[ob+2], b3 = bias[ob+3];
        #pragma unroll
        for (int nt = 0; nt < 2; nt++) {
            const f32x4 a = acc[ot][nt];
            const float v0 = a[0]+b0, v1 = a[1]+b1, v2 = a[2]+b2, v3 = a[3]+b3;
            if (ot < 2) {
                uint2 u;
                u.x = (u32)f2bf(v0) | ((u32)f2bf(v1) << 16);
                u.y = (u32)f2bf(v2) | ((u32)f2bf(v3) << 16);
                *(uint2*)&sh.ep.qk[16*nt + c16][16*T + 4*q] = u;
            } else {
                const int cb = 16*T - 128 + 4*q;
                sh.ep.vl[cb+0][16*nt + c16] = f2bf(v0);
                sh.ep.vl[cb+1][16*nt + c16] = f2bf(v1);
                sh.ep.vl[cb+2][16*nt + c16] = f2bf(v2);
                sh.ep.vl[cb+3][16*nt + c16] = f2bf(v3);
            }
        }
    }
    __syncthreads();

    {   // fragment-major global stores
        const int n    = t >> 3;
        const int c    = t & 7;
        const int g    = (n0 + n) >> 4;
        const int lane = 16*(c & 3) + (n & 15);
        const size_t dq = ((size_t)(b*256 + g))*1024 + (size_t)(c >> 2)*512 + lane*8;
        *(uint4*)&qF[dq] = *(uint4*)&sh.ep.qk[n][8*c];
        *(uint4*)&kF[dq] = *(uint4*)&sh.ep.qk[n][64 + 8*c];
        const int cg   = t >> 4, c16v = t & 15;
        const int pg   = n0 >> 5;
        u16* vdst = &vF[(((size_t)(b*16 + cg))*128 + pg)*512 + c16v*8];
        #pragma unroll
        for (int j = 0; j < 4; j++)          // lane 16j+c16v -> offset j*128
            *(uint4*)&vdst[j*128] = *(uint4*)&sh.ep.vl[t][8*j];
    }
}

// ---------------------------------------------------------------------------
// attn (FUSED softmax, R14): R13's b128-direct p2 layout + VALU diet, with
// the R11 carried-va double-buffer RESTORED (R13 post-mortem: in-region v
// loads had only ~150cyc exp/pack cover vs a full iteration (~5000cyc) in
// the carried scheme — PV stalled on vmcnt; VALUBusy fell 33.6->17.5 as
// predicted but MfmaUtil fell too; latency, not VALU, was exposed).
//  - p2[nj][m-octet][c16][2] uint2: PV reads ONE ds_read_b128 landing
//    directly as MFMA B-operand (no make_uint4). ~1 conflict cyc/read
//    (measured 2^20/dispatch) accepted: ~2-3us, < the ~10us mov savings.
//  - va for tile mt+1 prefetched during iter mt (rotation movs restored);
//    peeled tile 31 uses carried regs.
// Merged region: [BARRIER; QK_{mt+1}; van-prefetch_{mt+1};
// k-prefetch_{mt+2}; exp+z+write p[buf^1]; PV_mt(vac); rotate].
// grid 256 = 4b x 64 n-tiles, block 512, 1 blk/CU.
// ---------------------------------------------------------------------------
__global__ __launch_bounds__(512, 2) void attn_kernel(
    const u16* __restrict__ qF, const u16* __restrict__ kF, const u16* __restrict__ vF,
    const float* __restrict__ gamma,
    const float* __restrict__ x, float* __restrict__ out)
{
    __shared__ uint2 p2[2][2048];    // 2 x 16384 B
    __shared__ float zl[8][68];      // per-wave z partials (padded)

    const int t = threadIdx.x;
    const int w = t >> 6, l = t & 63, q = l >> 4, c16 = l & 15;

    const int id  = blockIdx.x;
    const int xcd = id & 7;                    // dispatch round-robins XCDs
    const int jb  = id >> 3;                   // 0..31
    const int b   = xcd >> 1;                  // 2 XCDs per batch -> L2 locality
    const int ntt = ((xcd & 1) << 5) | jb;     // 32 n-tiles per XCD
    const int n0  = ntt * 64;

    // persistent q B-fragments: group gn = ntt*4 + nj (block's 64 n-rows)
    bf16x8 qf[4][2];
    #pragma unroll
    for (int nj = 0; nj < 4; nj++) {
        const u16* qp = &qF[((size_t)(b*256 + ntt*4 + nj))*1024 + l*8];
        qf[nj][0] = *(const bf16x8*)qp;
        qf[nj][1] = *(const bf16x8*)(qp + 512);
    }

    f32x4 acc[2][4];   // [cg][nj]: c = 32w + 16cg + 4q + r, n = n0 + 16nj + c16
    #pragma unroll
    for (int cg = 0; cg < 2; cg++)
        #pragma unroll
        for (int nj = 0; nj < 4; nj++)
            acc[cg][nj] = (f32x4){0.f, 0.f, 0.f, 0.f};

    float zacc[4] = {0.f, 0.f, 0.f, 0.f};   // [nj]: n = n0 + 16nj + c16 partials

    // fragment-major bases (all lane-contiguous)
    const u16* kbase  = &kF[((size_t)(b*256 + w))*1024 + l*8];        // + mt*8192
    const u16* vbase0 = &vF[(((size_t)(b*16 + 2*w))*128)*512 + l*8];  // + (mt*4+kc)*512
    const u16* vbase1 = vbase0 + (size_t)128*512;                     // cg+1

    // p2 indices
    const int g   = 4*w + q;                       // m-quad within 128-m tile
    const int wb0 = (g>>1)*32 + c16*2 + (g&1);     // + nj*512   (uint2 idx)
    const int rb0 = q*16 + c16;                    // + nj*256 + kc*64 (uint4 idx)

    // ---- preload: va fragments for tile 0 (full-prologue latency cover) ----
    bf16x8 vac0[4], vac1[4];
    #pragma unroll
    for (int kc = 0; kc < 4; kc++) {
        vac0[kc] = *(const bf16x8*)(vbase0 + (size_t)kc*512);
        vac1[kc] = *(const bf16x8*)(vbase1 + (size_t)kc*512);
    }

    // ---- prologue: m-tile 0 scores -> p2[0]; stage tile-1 k ----
    bf16x8 ka0 = *(const bf16x8*)kbase;
    bf16x8 ka1 = *(const bf16x8*)(kbase + 512);
    {
        f32x4 s[4];
        #pragma unroll
        for (int nj = 0; nj < 4; nj++) {
            f32x4 a = {0.f, 0.f, 0.f, 0.f};
            a = MFMA32(ka0, qf[nj][0], a);
            a = MFMA32(ka1, qf[nj][1], a);
            s[nj] = a;
        }
        #pragma unroll
        for (int nj = 0; nj < 4; nj++) {
            const float p0 = EXP2F(s[nj][0]*L2E);
            const float p1 = EXP2F(s[nj][1]*L2E);
            const float p2v = EXP2F(s[nj][2]*L2E);
            const float p3 = EXP2F(s[nj][3]*L2E);
            zacc[nj] += (p0 + p1) + (p2v + p3);
            uint2 u;
            u.x = pack_trunc(p0, p1);
            u.y = pack_trunc(p2v, p3);
            p2[0][wb0 + nj*512] = u;
        }
    }
    ka0 = *(const bf16x8*)(kbase + 8192);        // m-tile 1
    ka1 = *(const bf16x8*)(kbase + 8192 + 512);

    int buf = 0;
    for (int mt = 0; mt < 31; mt++) {
        __syncthreads();
        // --- merged region ---
        // QK for m-tile mt+1 (k in registers)
        f32x4 s[4];
        #pragma unroll
        for (int nj = 0; nj < 4; nj++) {
            f32x4 a = {0.f, 0.f, 0.f, 0.f};
            a = MFMA32(ka0, qf[nj][0], a);
            a = MFMA32(ka1, qf[nj][1], a);
            s[nj] = a;
        }
        // prefetch NEXT tile's v fragments (full-iteration latency cover)
        bf16x8 van0[4], van1[4];
        #pragma unroll
        for (int kc = 0; kc < 4; kc++) {
            van0[kc] = *(const bf16x8*)(vbase0 + (size_t)((mt+1)*4 + kc)*512);
            van1[kc] = *(const bf16x8*)(vbase1 + (size_t)((mt+1)*4 + kc)*512);
        }
        // k prefetch for m-tile mt+2 (clamped)
        const int m2 = (mt < 30) ? mt + 2 : 31;
        ka0 = *(const bf16x8*)(kbase + (size_t)m2*8192);
        ka1 = *(const bf16x8*)(kbase + (size_t)m2*8192 + 512);

        // exp + z + write p2[buf^1] for m-tile mt+1
        #pragma unroll
        for (int nj = 0; nj < 4; nj++) {
            const float p0 = EXP2F(s[nj][0]*L2E);
            const float p1 = EXP2F(s[nj][1]*L2E);
            const float p2v = EXP2F(s[nj][2]*L2E);
            const float p3 = EXP2F(s[nj][3]*L2E);
            zacc[nj] += (p0 + p1) + (p2v + p3);
            uint2 u;
            u.x = pack_trunc(p0, p1);
            u.y = pack_trunc(p2v, p3);
            p2[buf^1][wb0 + nj*512] = u;
        }

        // PV for m-tile mt: b128 reads land directly as MFMA B-operand
        const uint4* pr = (const uint4*)p2[buf];
        #pragma unroll
        for (int nj = 0; nj < 4; nj++) {
            #pragma unroll
            for (int kc = 0; kc < 4; kc++) {
                const uint4 f = pr[rb0 + nj*256 + kc*64];
                const bf16x8 pf = *(const bf16x8*)&f;
                acc[0][nj] = MFMA32(vac0[kc], pf, acc[0][nj]);
                acc[1][nj] = MFMA32(vac1[kc], pf, acc[1][nj]);
            }
        }
        // rotate carried v fragments (compile-time indices)
        #pragma unroll
        for (int kc = 0; kc < 4; kc++) {
            vac0[kc] = van0[kc];
            vac1[kc] = van1[kc];
        }
        buf ^= 1;
    }
    // peeled final m-tile (31): PV only, va already carried in registers
    __syncthreads();
    {
        const uint4* pr = (const uint4*)p2[buf];
        #pragma unroll
        for (int nj = 0; nj < 4; nj++) {
            #pragma unroll
            for (int kc = 0; kc < 4; kc++) {
                const uint4 f = pr[rb0 + nj*256 + kc*64];
                const bf16x8 pf = *(const bf16x8*)&f;
                acc[0][nj] = MFMA32(vac0[kc], pf, acc[0][nj]);
                acc[1][nj] = MFMA32(vac1[kc], pf, acc[1][nj]);
            }
        }
    }

    // z: reduce over q (lanes ^16, ^32), then over waves via LDS
    #pragma unroll
    for (int nj = 0; nj < 4; nj++) {
        zacc[nj] += __shfl_xor(zacc[nj], 16, 64);
        zacc[nj] += __shfl_xor(zacc[nj], 32, 64);
    }
    if (q == 0) {
        #pragma unroll
        for (int nj = 0; nj < 4; nj++) zl[w][16*nj + c16] = zacc[nj];
    }
    __syncthreads();

    float rz[4];
    #pragma unroll
    for (int nj = 0; nj < 4; nj++) {
        float zt = 0.f;
        #pragma unroll
        for (int w8 = 0; w8 < 8; w8++) zt += zl[w8][16*nj + c16];
        rz[nj] = 1.0f / zt;
    }

    const float gm = gamma[0];
    #pragma unroll
    for (int cg = 0; cg < 2; cg++)
        #pragma unroll
        for (int nj = 0; nj < 4; nj++)
            #pragma unroll
            for (int r = 0; r < 4; r++) {
                const size_t o = ((size_t)(b*C_IN + 32*w + 16*cg + 4*q + r))*NPT
                               + n0 + 16*nj + c16;
                out[o] = gm*(acc[cg][nj][r]*rz[nj]) + x[o];
            }
}

// ---------------------------------------------------------------------------
extern "C" void kernel_launch(void* const* d_in, const int* in_sizes, int n_in,
                              void* d_out, int out_size, void* d_ws, size_t ws_size,
                              hipStream_t stream)
{
    const float* x     = (const float*)d_in[0];
    const float* wq    = (const float*)d_in[1];
    const float* bq    = (const float*)d_in[2];
    const float* wk    = (const float*)d_in[3];
    const float* bk    = (const float*)d_in[4];
    const float* wv    = (const float*)d_in[5];
    const float* bv    = (const float*)d_in[6];
    const float* gamma = (const float*)d_in[7];
    float* out = (float*)d_out;

    u16* qF  = (u16*)d_ws;                              // 2 MB
    u16* kF  = qF  + (size_t)NB*NPT*CQD;                // 2 MB
    u16* vF  = kF  + (size_t)NB*NPT*CQD;                // 8 MB
    u16* wbf = vF  + (size_t)NB*C_IN*NPT;               // 192 KB
    float* bias = (float*)(wbf + 384*256);              // 384

    prep_kernel<<<dim3(386), 256, 0, stream>>>(wq, bq, wk, bk, wv, bv, wbf, bias);
    proj_kernel<<<dim3(NPT/32, NB), 256, 0, stream>>>(x, wbf, bias, qF, kF, vF);
    attn_kernel<<<dim3(256), 512, 0, stream>>>(qF, kF, vF, gamma, x, out);
}